// Round 2
// baseline (97.301 us; speedup 1.0000x reference)
//
#include <hip/hip_runtime.h>
#include <math.h>

#define NCH 384
#define RNK 5
#define NA  32

// ws 4-byte-word layout
#define WS_NUM   0                    // RNK*NCH floats: numerator[r][c]
#define WS_NANW  (RNK*NCH)            // NCH floats: nan weight per channel
#define WS_TOT   (RNK*NCH + NCH)      // 1 float: total weight
#define WS_MIN   (RNK*NCH + NCH + 1)  // 1 uint: encoded global min of lik_data
#define WS_WORDS (RNK*NCH + NCH + 2)

#define ACC_GRID 1024
#define MAX_PER  16

__device__ __forceinline__ bool finitef(float v) {
    return fabsf(v) <= 3.402823466e38f;   // NaN fails, +-inf exceeds
}

// order-preserving float<->uint encoding for atomicMin
__device__ __forceinline__ unsigned fenc(float f) {
    unsigned u = __float_as_uint(f);
    return (u & 0x80000000u) ? ~u : (u | 0x80000000u);
}
__device__ __forceinline__ float fdec(unsigned u) {
    unsigned b = (u & 0x80000000u) ? (u ^ 0x80000000u) : ~u;
    return __uint_as_float(b);
}

__global__ void init_ws_kernel(unsigned* __restrict__ ws) {
    int i = blockIdx.x * blockDim.x + threadIdx.x;
    if (i < WS_WORDS) ws[i] = (i == WS_MIN) ? 0xFFFFFFFFu : 0u;
}

// One work item per (spike, channel-slot): loads fully coalesced, LDS atomic
// pattern = 32 consecutive channels per spike -> every bank hit exactly twice
// per wave (free). Grid-stride so the per-block LDS bins flush only once.
__global__ __launch_bounds__(256) void accum_kernel(
    const float* __restrict__ feats,     // (n, RNK, NA)
    const int*   __restrict__ channels,  // (n, NA) flat == idx
    const float* __restrict__ weights,   // (n,)
    float* __restrict__ ws, int n)
{
    __shared__ float s_num[RNK * NCH];
    __shared__ float s_nanw[NCH];
    __shared__ float s_total;
    const int tid = threadIdx.x;
    for (int i = tid; i < RNK * NCH; i += 256) s_num[i] = 0.f;
    for (int i = tid; i < NCH; i += 256) s_nanw[i] = 0.f;
    if (tid == 0) s_total = 0.f;
    __syncthreads();

    const int total = n * NA;
    const int stride = gridDim.x * blockDim.x;
    float tw = 0.f;
    for (int idx = blockIdx.x * blockDim.x + tid; idx < total; idx += stride) {
        const int spike = idx >> 5;
        const int a     = idx & (NA - 1);
        const int ch    = channels[idx];
        const float w   = weights[spike];
        if (a == 0) tw += w;                   // each spike counted once
        const float* f = feats + (size_t)spike * (RNK * NA) + a;
        const float v0 = f[0];
        if (finitef(v0)) {
            atomicAdd(&s_num[ch], w * v0);
            #pragma unroll
            for (int r = 1; r < RNK; ++r) {
                float v = f[r * NA];
                if (!finitef(v)) v = 0.f;      // nan_to_num (mask shared across ranks)
                atomicAdd(&s_num[r * NCH + ch], w * v);
            }
        } else {
            atomicAdd(&s_nanw[ch], w);
        }
    }

    #pragma unroll
    for (int off = 32; off; off >>= 1) tw += __shfl_down(tw, off);
    if ((tid & 63) == 0) atomicAdd(&s_total, tw);
    __syncthreads();

    for (int i = tid; i < RNK * NCH; i += 256) {
        float v = s_num[i];
        if (v != 0.f) atomicAdd(&ws[WS_NUM + i], v);
    }
    for (int i = tid; i < NCH; i += 256) {
        float v = s_nanw[i];
        if (v != 0.f) atomicAdd(&ws[WS_NANW + i], v);
    }
    if (tid == 0) atomicAdd(&ws[WS_TOT], s_total);
}

__global__ void finalize_kernel(const float* __restrict__ ws,
                                float* __restrict__ out) {
    int i = blockIdx.x * blockDim.x + threadIdx.x;
    if (i < RNK * NCH) {
        int c = i % NCH;
        float total = ws[WS_TOT];
        float cnt = total - ws[WS_NANW + c];
        out[i] = ws[WS_NUM + i] / cnt;
    }
}

__global__ void min_reduce_kernel(const float* __restrict__ data, int nnz,
                                  unsigned* __restrict__ minw) {
    float m = 3.402823466e38f;
    int i = blockIdx.x * blockDim.x + threadIdx.x;
    const int stride = gridDim.x * blockDim.x;
    int n4 = nnz >> 2;
    const float4* d4 = (const float4*)data;
    for (int j = i; j < n4; j += stride) {
        float4 v = d4[j];
        m = fminf(m, fminf(fminf(v.x, v.y), fminf(v.z, v.w)));
    }
    for (int j = (n4 << 2) + i; j < nnz; j += stride) m = fminf(m, data[j]);
    #pragma unroll
    for (int off = 32; off; off >>= 1) m = fminf(m, __shfl_down(m, off));
    if ((threadIdx.x & 63) == 0) atomicMin(minw, fenc(m));
}

// Stage each block's 256*per (data,row) pairs through LDS with coalesced
// global loads; per-thread scan reads LDS at stride `per` (2-way bank
// alias for per=10 -> free).
__global__ __launch_bounds__(256) void assign_kernel(
    const int*   __restrict__ rows,
    const float* __restrict__ data,
    const unsigned* __restrict__ ws,
    float* __restrict__ out, int n, int per)
{
    __shared__ float sd[256 * MAX_PER];
    __shared__ int   sr[256 * MAX_PER];
    const int tid = threadIdx.x;
    const int base = blockIdx.x * 256;
    const float offset = fdec(ws[WS_MIN]) - 1.0f;

    if (per <= MAX_PER) {
        const int lim = min(256, n - base) * per;
        const size_t gbase = (size_t)base * per;
        for (int i = tid; i < lim; i += 256) {
            sd[i] = data[gbase + i];
            sr[i] = rows[gbase + i];
        }
        __syncthreads();
        const int spike = base + tid;
        if (spike >= n) return;
        float best_s = -3.402823466e38f;
        int best_row = 0x7FFFFFFF;
        const int o = tid * per;
        for (int j = 0; j < per; ++j) {
            float s = sd[o + j] - offset;   // same f32 op as reference's `shifted`
            int r = sr[o + j];
            if (s > best_s) { best_s = s; best_row = r; }
            else if (s == best_s && r < best_row) best_row = r;
        }
        out[RNK * NCH + spike] = (float)best_row;
    } else {
        const int spike = base + tid;
        if (spike >= n) return;
        const float* d  = data + (size_t)spike * per;
        const int*   rr = rows + (size_t)spike * per;
        float best_s = -3.402823466e38f;
        int best_row = 0x7FFFFFFF;
        for (int j = 0; j < per; ++j) {
            float s = d[j] - offset;
            int r = rr[j];
            if (s > best_s) { best_s = s; best_row = r; }
            else if (s == best_s && r < best_row) best_row = r;
        }
        out[RNK * NCH + spike] = (float)best_row;
    }
}

extern "C" void kernel_launch(void* const* d_in, const int* in_sizes, int n_in,
                              void* d_out, int out_size, void* d_ws, size_t ws_size,
                              hipStream_t stream) {
    const float* feats    = (const float*)d_in[0];
    const int*   channels = (const int*)d_in[1];
    const float* weights  = (const float*)d_in[2];
    const int*   lik_rows = (const int*)d_in[3];
    // d_in[4] = lik_cols: structurally repeat(arange(n), per), not needed
    const float* lik_data = (const float*)d_in[5];

    int n   = in_sizes[2];
    int nnz = in_sizes[3];
    int per = nnz / n;

    float*    out = (float*)d_out;
    unsigned* wsu = (unsigned*)d_ws;
    float*    wsf = (float*)d_ws;

    init_ws_kernel<<<(WS_WORDS + 255) / 256, 256, 0, stream>>>(wsu);
    accum_kernel<<<ACC_GRID, 256, 0, stream>>>(feats, channels, weights, wsf, n);
    finalize_kernel<<<(RNK * NCH + 255) / 256, 256, 0, stream>>>(wsf, out);
    min_reduce_kernel<<<256, 256, 0, stream>>>(lik_data, nnz, wsu + WS_MIN);
    assign_kernel<<<(n + 255) / 256, 256, 0, stream>>>(lik_rows, lik_data, wsu, out, n, per);
}